// Round 4
// baseline (360.567 us; speedup 1.0000x reference)
//
#include <hip/hip_runtime.h>
#include <cstdint>
#include <cstddef>

#define NPTS 8192
#define DDIM 128
#define BATCH 2
#define NROWS (BATCH * NPTS)
#define EPSGAP 0.02f
#define NCOLT 64   // 8192 / 128 column tiles (partials per row)
#define RCAP 2048  // candidate-list capacity in recheck

typedef __attribute__((ext_vector_type(8))) short short8v;
typedef __attribute__((ext_vector_type(4))) float f32x4;

typedef __attribute__((address_space(3))) unsigned int as3_uint;
typedef const __attribute__((address_space(1))) unsigned int as1_uint;

static __device__ __forceinline__ unsigned short f2bf_rne(float x) {
    unsigned int u = __float_as_uint(x);
    unsigned int r = (u + 0x7FFFu + ((u >> 16) & 1u)) >> 16;
    return (unsigned short)r;
}
static __device__ __forceinline__ float bf2f(unsigned short h) {
    return __uint_as_float(((unsigned int)h) << 16);
}

// ---- vectorized zero-fill of d_out (537 MB): 16B/lane grid-stride -------------
__global__ __launch_bounds__(256) void fill0_kernel(float4* __restrict__ out, size_t n4) {
    size_t i = (size_t)blockIdx.x * 256 + threadIdx.x;
    const size_t stride = (size_t)gridDim.x * 256;
    const float4 z = {0.0f, 0.0f, 0.0f, 0.0f};
    for (; i < n4; i += stride) out[i] = z;
}

// ---- split fp32 -> [xh(128) | xl(128)] bf16 rows; optional fused y2 -----------
__global__ void split_kernel(const float* __restrict__ src, unsigned short* __restrict__ dst,
                             float* __restrict__ y2 /* nullptr to skip */) {
    size_t t = (size_t)blockIdx.x * 256 + threadIdx.x;   // one per 4 elems
    size_t row = t >> 5;
    int kc = (int)(t & 31) * 4;
    float4 v = reinterpret_cast<const float4*>(src)[t];
    float xs[4] = {v.x, v.y, v.z, v.w};
    ushort4 h, l;
    unsigned short hh[4], ll[4];
#pragma unroll
    for (int e = 0; e < 4; ++e) {
        float x = xs[e];
        unsigned short hb = f2bf_rne(x);
        float lo = x - bf2f(hb);
        hh[e] = hb; ll[e] = f2bf_rne(lo);
    }
    h.x = hh[0]; h.y = hh[1]; h.z = hh[2]; h.w = hh[3];
    l.x = ll[0]; l.y = ll[1]; l.z = ll[2]; l.w = ll[3];
    *reinterpret_cast<ushort4*>(&dst[row * 256 + kc])       = h;
    *reinterpret_cast<ushort4*>(&dst[row * 256 + 128 + kc]) = l;

    if (y2 != nullptr) {
        // 32 consecutive threads own one row (t&31 = chunk); reduce sum of squares
        float s = fmaf(v.x, v.x, fmaf(v.y, v.y, fmaf(v.z, v.z, v.w * v.w)));
#pragma unroll
        for (int off = 16; off >= 1; off >>= 1) s += __shfl_xor(s, off);
        if ((t & 31) == 0) y2[row] = s;
    }
}

// ---- MFMA GEMM (K=384 emulating fp32 via bf16 hi/lo) + top-2 argmin epilogue --
__global__ __launch_bounds__(256) void gemm_mfma(
    const unsigned short* __restrict__ Aext,  // [B][N][256] = [xh|xl]
    const unsigned short* __restrict__ Bext,
    const float* __restrict__ y2g,
    float* __restrict__ pv1, float* __restrict__ pv2, unsigned int* __restrict__ pidx)
{
    __shared__ short As[128 * 64];
    __shared__ short Bs[128 * 64];
    __shared__ float rv1[2][128];
    __shared__ float rv2[2][128];
    __shared__ unsigned int ri[2][128];

    const int tid  = threadIdx.x;
    const int lane = tid & 63;
    const int wid  = tid >> 6;
    const int wr   = wid >> 1, wc = wid & 1;
    const int l15  = lane & 15, l4 = lane >> 4;
    const int bm   = blockIdx.x;
    const int bnc  = blockIdx.y;
    const int b    = blockIdx.z;
    const int row0 = bm * 128, col0 = bnc * 128;

    const unsigned short* Abase = Aext + ((size_t)b * NPTS + row0) * 256;
    const unsigned short* Bbase = Bext + ((size_t)b * NPTS + col0) * 256;

    f32x4 acc[4][4];
#pragma unroll
    for (int i = 0; i < 4; ++i)
#pragma unroll
        for (int j = 0; j < 4; ++j) acc[i][j] = (f32x4)0.0f;

    const int akoff[6] = {0, 64, 128, 192, 0, 64};   // xh,xh,xl,xl,xh,xh
    const int bkoff[6] = {0, 64, 0, 64, 128, 192};   // yh,yh,yh,yh,yl,yl

#pragma unroll
    for (int kk = 0; kk < 6; ++kk) {
        __syncthreads();
        {
            const int ka = akoff[kk], kb = bkoff[kk];
#pragma unroll
            for (int it = 0; it < 4; ++it) {
                int flat = it * 256 + tid;
                int r = flat >> 3, kc = flat & 7;
                int kcs = kc ^ (r & 7);
                const unsigned short* ga = Abase + (size_t)r * 256 + ka + kcs * 8;
                const unsigned short* gb = Bbase + (size_t)r * 256 + kb + kcs * 8;
                __builtin_amdgcn_global_load_lds((as1_uint*)ga, (as3_uint*)&As[flat * 8], 16, 0, 0);
                __builtin_amdgcn_global_load_lds((as1_uint*)gb, (as3_uint*)&Bs[flat * 8], 16, 0, 0);
            }
        }
        __syncthreads();
#pragma unroll
        for (int ks = 0; ks < 2; ++ks) {
            short8v a[4], bf[4];
#pragma unroll
            for (int i = 0; i < 4; ++i) {
                int ra = wr * 64 + i * 16 + l15;
                int ch = ks * 4 + l4;
                a[i] = *reinterpret_cast<const short8v*>(&As[ra * 64 + ((ch ^ (ra & 7)) << 3)]);
            }
#pragma unroll
            for (int j = 0; j < 4; ++j) {
                int rb = wc * 64 + j * 16 + l15;
                int ch = ks * 4 + l4;
                bf[j] = *reinterpret_cast<const short8v*>(&Bs[rb * 64 + ((ch ^ (rb & 7)) << 3)]);
            }
#pragma unroll
            for (int i = 0; i < 4; ++i)
#pragma unroll
                for (int j = 0; j < 4; ++j)
                    acc[i][j] = __builtin_amdgcn_mfma_f32_16x16x32_bf16(a[i], bf[j], acc[i][j], 0, 0, 0);
        }
    }

    const float* y2b = y2g + b * NPTS;
    float yv[4];
#pragma unroll
    for (int j = 0; j < 4; ++j) yv[j] = y2b[col0 + wc * 64 + j * 16 + l15];

#pragma unroll
    for (int i = 0; i < 4; ++i) {
#pragma unroll
        for (int q = 0; q < 4; ++q) {
            float v1 = INFINITY, v2 = INFINITY;
            unsigned int mi = 0u;
#pragma unroll
            for (int j = 0; j < 4; ++j) {
                const float v = fmaf(-2.0f, acc[i][j][q], yv[j]);
                const unsigned int m = (unsigned)(col0 + wc * 64 + j * 16 + l15);
                if (v < v1) { v2 = v1; v1 = v; mi = m; }
                else        { v2 = fminf(v2, v); }
            }
#pragma unroll
            for (int off = 1; off < 16; off <<= 1) {
                float o1 = __shfl_xor(v1, off);
                float o2 = __shfl_xor(v2, off);
                unsigned int oi = __shfl_xor(mi, off);
                if (o1 < v1 || (o1 == v1 && oi < mi)) { v2 = fminf(v1, o2); v1 = o1; mi = oi; }
                else                                  { v2 = fminf(v2, fminf(o1, o2)); }
            }
            if (l15 == 0) {
                const int rl = wr * 64 + i * 16 + l4 * 4 + q;
                rv1[wc][rl] = v1; rv2[wc][rl] = v2; ri[wc][rl] = mi;
            }
        }
    }
    __syncthreads();
    if (tid < 128) {
        float a1 = rv1[0][tid], a2 = rv2[0][tid];
        unsigned int ai = ri[0][tid];
        const float o1 = rv1[1][tid], o2 = rv2[1][tid];
        const unsigned int oi = ri[1][tid];
        if (o1 < a1 || (o1 == a1 && oi < ai)) { a2 = fminf(a1, o2); a1 = o1; ai = oi; }
        else                                  { a2 = fminf(a2, fminf(o1, o2)); }
        const size_t gr = (size_t)b * NPTS + row0 + tid;
        pv1[(size_t)bnc * NROWS + gr] = a1;
        pv2[(size_t)bnc * NROWS + gr] = a2;
        pidx[(size_t)bnc * NROWS + gr] = ai;
    }
}

// ---- merge the 64 column-tile partials; compact near-tie rows into a list -----
__global__ void resolve_kernel(const float* __restrict__ pv1, const float* __restrict__ pv2,
                               const unsigned int* __restrict__ pidx,
                               unsigned int* __restrict__ idxFinal, float* __restrict__ bestval,
                               unsigned int* __restrict__ flagList, unsigned int* __restrict__ flagCount)
{
    const int gr = blockIdx.x * 256 + threadIdx.x;
    float a1 = INFINITY, a2 = INFINITY;
    unsigned int ai = 0u;
    for (int cs = 0; cs < NCOLT; ++cs) {
        const float o1 = pv1[(size_t)cs * NROWS + gr];
        const float o2 = pv2[(size_t)cs * NROWS + gr];
        const unsigned int oi = pidx[(size_t)cs * NROWS + gr];
        if (o1 < a1 || (o1 == a1 && oi < ai)) { a2 = fminf(a1, o2); a1 = o1; ai = oi; }
        else                                  { a2 = fminf(a2, fminf(o1, o2)); }
    }
    idxFinal[gr] = ai;
    bestval[gr] = a1;
    if (a2 - a1 < EPSGAP) {
        unsigned int pos = atomicAdd(flagCount, 1u);
        flagList[pos] = (unsigned int)gr;
    }
}

// ---- candidate-window fp64 recheck (fixed grid, grid-strides the flag list) ---
__global__ __launch_bounds__(256) void recheck_kernel(
    const float* __restrict__ f0, const float* __restrict__ f1,
    const float* __restrict__ pv1, const float* __restrict__ pv2,
    const unsigned int* __restrict__ pidx, const float* __restrict__ bestval,
    const unsigned int* __restrict__ flagList, const unsigned int* __restrict__ flagCount,
    unsigned int* __restrict__ idxFinal)
{
    __shared__ float xrow[DDIM];
    __shared__ unsigned int cand[RCAP];
    __shared__ int ncand;
    __shared__ double redv[256];
    __shared__ unsigned int redi[256];

    const int tid = threadIdx.x;
    const unsigned int nflag = *flagCount;

    for (unsigned int li = blockIdx.x; li < nflag; li += gridDim.x) {
        const int gr = (int)flagList[li];
        const int b = gr >> 13, n = gr & (NPTS - 1);
        const float W = bestval[gr] + EPSGAP;

        if (tid == 0) ncand = 0;
        if (tid < DDIM) xrow[tid] = f0[((size_t)b * NPTS + n) * DDIM + tid];
        __syncthreads();

        if (tid < NCOLT) {
            const size_t base = (size_t)tid * NROWS + gr;
            const float t1 = pv1[base];
            if (t1 <= W) {
                if (pv2[base] <= W) {
                    int p = atomicAdd(&ncand, 128);
                    if (p + 128 <= RCAP)
                        for (int c = 0; c < 128; ++c) cand[p + c] = (unsigned)(tid * 128 + c);
                } else {
                    int p = atomicAdd(&ncand, 1);
                    if (p < RCAP) cand[p] = pidx[base];
                }
            }
        }
        __syncthreads();

        const int nc = ncand;
        double bv = 1e300;
        unsigned int bi = 0xFFFFFFFFu;
        if (nc <= RCAP) {
            for (int c = tid; c < nc; c += 256) {
                const unsigned int m = cand[c];
                const float4* ypv = reinterpret_cast<const float4*>(f1 + ((size_t)b * NPTS + m) * DDIM);
                const float4* xpv = reinterpret_cast<const float4*>(xrow);
                double s0 = 0.0, s1 = 0.0, s2 = 0.0, s3 = 0.0;
#pragma unroll 8
                for (int k4 = 0; k4 < DDIM / 4; ++k4) {
                    const float4 y = ypv[k4];
                    const float4 x = xpv[k4];
                    s0 = fma((double)y.x, (double)y.x - 2.0 * (double)x.x, s0);
                    s1 = fma((double)y.y, (double)y.y - 2.0 * (double)x.y, s1);
                    s2 = fma((double)y.z, (double)y.z - 2.0 * (double)x.z, s2);
                    s3 = fma((double)y.w, (double)y.w - 2.0 * (double)x.w, s3);
                }
                const double v = (s0 + s1) + (s2 + s3);
                if (v < bv || (v == bv && m < bi)) { bv = v; bi = m; }
            }
        } else {
            for (int m = tid; m < NPTS; m += 256) {
                const float4* ypv = reinterpret_cast<const float4*>(f1 + ((size_t)b * NPTS + m) * DDIM);
                const float4* xpv = reinterpret_cast<const float4*>(xrow);
                double s0 = 0.0, s1 = 0.0, s2 = 0.0, s3 = 0.0;
#pragma unroll 4
                for (int k4 = 0; k4 < DDIM / 4; ++k4) {
                    const float4 y = ypv[k4];
                    const float4 x = xpv[k4];
                    s0 = fma((double)y.x, (double)y.x - 2.0 * (double)x.x, s0);
                    s1 = fma((double)y.y, (double)y.y - 2.0 * (double)x.y, s1);
                    s2 = fma((double)y.z, (double)y.z - 2.0 * (double)x.z, s2);
                    s3 = fma((double)y.w, (double)y.w - 2.0 * (double)x.w, s3);
                }
                const double v = (s0 + s1) + (s2 + s3);
                if (v < bv || (v == bv && (unsigned)m < bi)) { bv = v; bi = (unsigned)m; }
            }
        }
        redv[tid] = bv; redi[tid] = bi;
        __syncthreads();
        for (int s = 128; s >= 1; s >>= 1) {
            if (tid < s) {
                const double ov = redv[tid + s]; const unsigned int oi = redi[tid + s];
                if (ov < redv[tid] || (ov == redv[tid] && oi < redi[tid])) { redv[tid] = ov; redi[tid] = oi; }
            }
            __syncthreads();
        }
        if (tid == 0) idxFinal[gr] = redi[0];
        __syncthreads();
    }
}

// ---- write one-hot 1.0s and idx-as-float tail ---------------------------------
__global__ void scatter_kernel(const unsigned int* __restrict__ idxFinal, float* __restrict__ out) {
    const int gr = blockIdx.x * 256 + threadIdx.x;
    const unsigned int idx = idxFinal[gr];
    out[(size_t)gr * NPTS + idx] = 1.0f;
    out[(size_t)BATCH * NPTS * NPTS + gr] = (float)idx;
}

extern "C" void kernel_launch(void* const* d_in, const int* in_sizes, int n_in,
                              void* d_out, int out_size, void* d_ws, size_t ws_size,
                              hipStream_t stream)
{
    const float* f0 = (const float*)d_in[0];
    const float* f1 = (const float*)d_in[1];
    float* out = (float*)d_out;

    // ws layout (bytes): Aext 8.39M | Bext 8.39M | y2 64K | pv1 4.19M | pv2 4.19M
    //                    | pidx 4.19M | idxFinal 64K | bestval 64K | flagList 64K
    //                    | flagCount 4  (~29.8 MB)
    char* wsb = (char*)d_ws;
    unsigned short* Aext = (unsigned short*)wsb;                  wsb += (size_t)BATCH * NPTS * 256 * 2;
    unsigned short* Bext = (unsigned short*)wsb;                  wsb += (size_t)BATCH * NPTS * 256 * 2;
    float* y2            = (float*)wsb;                           wsb += (size_t)NROWS * 4;
    float* pv1           = (float*)wsb;                           wsb += (size_t)NCOLT * NROWS * 4;
    float* pv2           = (float*)wsb;                           wsb += (size_t)NCOLT * NROWS * 4;
    unsigned int* pidx   = (unsigned int*)wsb;                    wsb += (size_t)NCOLT * NROWS * 4;
    unsigned int* idxFinal = (unsigned int*)wsb;                  wsb += (size_t)NROWS * 4;
    float* bestval       = (float*)wsb;                           wsb += (size_t)NROWS * 4;
    unsigned int* flagList = (unsigned int*)wsb;                  wsb += (size_t)NROWS * 4;
    unsigned int* flagCount = (unsigned int*)wsb;

    // out_size = 2*8192*8192 + 16384 floats = 33,558,528 float4s (divisible by 4)
    const size_t n4 = (size_t)out_size / 4;
    fill0_kernel<<<2048, 256, 0, stream>>>((float4*)out, n4);
    hipMemsetAsync(flagCount, 0, 4, stream);

    split_kernel<<<(BATCH * NPTS * 32) / 256, 256, 0, stream>>>(f0, Aext, nullptr);
    split_kernel<<<(BATCH * NPTS * 32) / 256, 256, 0, stream>>>(f1, Bext, y2);
    gemm_mfma<<<dim3(NPTS / 128, NPTS / 128, BATCH), 256, 0, stream>>>(Aext, Bext, y2, pv1, pv2, pidx);
    resolve_kernel<<<NROWS / 256, 256, 0, stream>>>(pv1, pv2, pidx, idxFinal, bestval, flagList, flagCount);
    recheck_kernel<<<1024, 256, 0, stream>>>(f0, f1, pv1, pv2, pidx, bestval, flagList, flagCount, idxFinal);
    scatter_kernel<<<NROWS / 256, 256, 0, stream>>>(idxFinal, out);
}